// Round 3
// baseline (190.299 us; speedup 1.0000x reference)
//
#include <hip/hip_runtime.h>
#include <stdint.h>

// x [3,5,32,64,32,32] binary float -> per 32x32 image max(component size, bg count)
// -> sum over 64 patches >> 6 -> float [480].
//
// ONE wave per block, TWO images per wave: lanes 0-31 own image A's rows,
// lanes 32-63 image B's. 1-wave workgroups free LDS/slots per-wave (no
// intra-block skew hostage), so the data-dependent union-find runtime skew
// backfills across ~32 resident waves/CU instead of 8 coarse blocks.
//
// LOAD: fully coalesced. Load instr j reads words pairBase + j*256 + lane*4
// (contiguous 1 KB per wave per instruction -> 16 cache lines). Each uint4
// packs to a 4-bit nibble; 8 nibbles accumulate into one word W per lane.
// Repack to row-per-lane masks: owner lane L's pixel p=L*32+k sits in instr
// j=L>>3, source lane sl=(L&7)*8+(k>>2), nibble bit k&3.
//
// Runs numbered by segmented 64-lane scan (fg popcount packed into the same
// scan, high 16 bits). Edge phase: lock-free union with atomicCAS hooking
// LARGER ROOT -> SMALLER ROOT; JOINT dual-chain find with path halving +
// current-run root caches for BOTH endpoints. Then 2 rounds of PARALLEL
// pointer-jumping flatten the forest (strided, independent -> pipelined;
// parent reads hit roots -> same-address broadcast, conflict-free), so the
// count phase is a single read + atomicAdd per run (L[r] = r | size<<9).
// Wave-lockstep => no barriers.

#define N_IMGS 30720
#define N_OUT  480

// Serial find with path halving (used only on rare CAS-retry / deep paths).
__device__ __forceinline__ int findH(int* L, int i) {
    for (;;) {
        int p = L[i] & 511;
        if (p == i) return i;
        int g = L[p] & 511;
        if (g == p) return p;
        L[i] = g;          // halving: shortcut to grandparent (monotone-safe)
        i = g;
    }
}

__global__ __launch_bounds__(64)
void ccl_wave2_kernel(const uint32_t* __restrict__ x, int* __restrict__ maxc) {
    __shared__ int Lbuf[2 * 512];                // 4 KiB: two images

    const int lane = threadIdx.x;                // 0..63
    const int half = lane >> 5;                  // 0: image A, 1: image B
    const int row  = lane & 31;
    const size_t img = (size_t)blockIdx.x * 2 + half;
    int* L = Lbuf + half * 512;

    // ---- coalesced load + nibble pack: 8 x uint4, 1 KB/wave/instr ----
    const size_t pairBase = (size_t)blockIdx.x * 2048;
    const uint4* wp = (const uint4*)(x + pairBase) + lane;
    uint32_t W = 0;
    #pragma unroll
    for (int j = 0; j < 8; ++j) {
        uint4 q = wp[j * 64];                    // words pairBase + j*256 + lane*4
        uint32_t n = (q.x >> 29) | ((q.y >> 29) << 1)
                   | ((q.z >> 29) << 2) | ((q.w >> 29) << 3);
        W |= n << (4 * j);
    }

    // ---- repack to row-per-lane: 8 shuffles + shifts ----
    const int slBase = (lane & 7) * 8;           // first source lane
    const int jsh    = (lane >> 3) * 4;          // my instr's nibble shift
    uint32_t m = 0;
    #pragma unroll
    for (int t = 0; t < 8; ++t) {
        uint32_t sv = (uint32_t)__shfl((int)W, slBase + t);
        m |= ((sv >> jsh) & 0xFu) << (4 * t);
    }

    // ---- run numbering + fg count: ONE 64-lane inclusive scan, segmented at
    // lane 32. Packed word: low 16 = run count, high 16 = popcount. ----
    uint32_t runStarts = m & ~(m << 1);
    int nruns = __popc(runStarts);
    int packed = nruns | (__popc(m) << 16);
    int scan = packed;
    #pragma unroll
    for (int off = 1; off < 64; off <<= 1) {
        int u = __shfl_up(scan, off);
        if (lane >= off) scan += u;
    }
    const int totalA   = __shfl(scan, 31);
    const int totalAll = __shfl(scan, 63);
    const int myTotal  = half ? (totalAll - totalA) : totalA;
    // low fields never borrow (inclusive scan >= own; half-B scan >= totalA)
    const int base = (scan - packed - (half ? totalA : 0)) & 0xFFFF;
    const int R    = myTotal & 0xFFFF;           // runs in my image
    const int fg   = myTotal >> 16;              // foreground pixels, my image

    for (int i = row; i < R; i += 32) L[i] = i;  // bank-conflict-free init

    // ---- edges: one per overlap segment with previous row ----
    uint32_t mprev  = __shfl_up(m, 1);
    uint32_t rsPrev = __shfl_up(runStarts, 1);
    int      bPrev  = __shfl_up(base, 1);
    if (row == 0) mprev = 0;                 // row 0 of each image
    uint32_t ov  = m & mprev;
    uint32_t ovs = ov & ~(ov << 1);

    int lastA = -1, rootA = -1;              // cache: root of current lower run
    int lastB = -1, rootB = -1;              // cache: root of current upper run
    while (ovs) {
        int c = __ffs(ovs) - 1; ovs &= ovs - 1;
        uint32_t mc = (2u << c) - 1;         // bits 0..c (c=31 -> all ones)
        int a = base  + __popc(runStarts & mc) - 1;
        int b = bPrev + __popc(rsPrev    & mc) - 1;

        int ra = (a == lastA) ? rootA : a;   // reuse merged roots if same run
        int rb = (b == lastB) ? rootB : b;
        // joint dual-chain find: both chains advance 2 levels per iteration;
        // the 4 LDS reads are independent and pipeline in the queue.
        for (;;) {
            int pa = L[ra] & 511;
            int pb = L[rb] & 511;
            if (pa == ra && pb == rb) break;
            int ga = L[pa] & 511;            // grandparents (independent)
            int gb = L[pb] & 511;
            if (pa != ra) { L[ra] = ga; ra = ga; }
            if (pb != rb) { L[rb] = gb; rb = gb; }
        }
        while (ra != rb) {                   // hook larger ROOT to smaller
            int hi = ra > rb ? ra : rb;
            int lo = ra ^ rb ^ hi;
            int old = atomicCAS(&L[hi], hi, lo);
            if (old == hi) { ra = lo; break; }   // hooked; merged root = lo
            ra = findH(L, old & 511);        // root moved; chase and retry
            rb = lo;
        }
        lastA = a; rootA = ra; lastB = b; rootB = ra;
    }
    // wave reconverges here: all unions complete before any lane proceeds.

    // ---- parallel flatten: 2 rounds of pointer jumping over all runs.
    // During this phase L entries are pure parent indices (<512): size bits
    // are only added afterwards. Strided i -> conflict-free reads/writes;
    // parent reads cluster at roots -> same-address broadcast (free).
    // Independent across i within a round -> LDS reads pipeline. ----
    #pragma unroll
    for (int rnd = 0; rnd < 2; ++rnd) {
        for (int i = row; i < R; i += 32) {
            int p = L[i];
            int g = L[p];
            if (g != p) L[i] = g;            // depth halves per round
        }
    }

    // ---- count phase: single-read resolve (+rare fallback) + size add.
    // L[r] = r | (size<<9); adds never touch low 9 bits. ----
    uint32_t mm = m;
    int idx = base;
    while (mm) {
        int s = __ffs(mm) - 1;
        uint32_t t  = mm + (1u << s);
        uint32_t rm = (t ^ mm) & mm;         // this run's bits
        mm &= ~rm;
        int r1 = L[idx] & 511;               // depth <=1 after flatten
        int p  = L[r1] & 511;                // root verify (broadcast read)
        if (p != r1) r1 = findH(L, p);       // rare deep fallback
        atomicAdd(&L[r1], __popc(rm) << 9);
        ++idx;
    }

    // ---- max component size, per image (strided, conflict-free) ----
    int mx = 0;
    for (int i = row; i < R; i += 32) {
        int v = L[i];
        if ((v & 511) == i) mx = max(mx, v >> 9);
    }
    #pragma unroll
    for (int off = 1; off < 32; off <<= 1) mx = max(mx, __shfl_xor(mx, off));

    if (row == 0) maxc[img] = max(mx, 1024 - fg);
}

__global__ __launch_bounds__(64)
void patch_reduce_kernel(const int* __restrict__ maxc, float* __restrict__ out) {
    const int o = blockIdx.x;   // 0..479
    int v = maxc[(size_t)o * 64 + threadIdx.x];
    #pragma unroll
    for (int off = 32; off > 0; off >>= 1)
        v += __shfl_down(v, off);
    if (threadIdx.x == 0) out[o] = (float)(v >> 6);  // integer division by 64
}

extern "C" void kernel_launch(void* const* d_in, const int* in_sizes, int n_in,
                              void* d_out, int out_size, void* d_ws, size_t ws_size,
                              hipStream_t stream) {
    const uint32_t* x = (const uint32_t*)d_in[0];   // float bits; 1.0f>>29 == 1
    float* out = (float*)d_out;
    int* maxc = (int*)d_ws;   // 30720 ints

    ccl_wave2_kernel<<<N_IMGS / 2, 64, 0, stream>>>(x, maxc);
    patch_reduce_kernel<<<N_OUT, 64, 0, stream>>>(maxc, out);
}